// Round 18
// baseline (33.244 us; speedup 1.0000x reference)
//
#include <hip/hip_runtime.h>

// Y[b,e,k,j] = sum_i X[b, ind[b,e,k], i] * W[e,i,j]
// X:[B,T,I] f32, ind:[B,E,K] int32, W:[E,I,J] f32 -> Y:[B,E,K,J] f32
#define B_ 8
#define T_ 8192
#define I_ 128
#define E_ 16
#define J_ 128
#define K_ 1024
#define ROWS 128   // k-rows per block (512 threads)

typedef unsigned short u16;
typedef unsigned int   u32;
typedef __attribute__((ext_vector_type(8))) short s8v;   // 8 bf16 = 4 VGPRs
typedef __attribute__((ext_vector_type(4))) float f4v;   // MFMA accumulator

__device__ __forceinline__ u16 f2bf(float f) {
    union { float f; u32 u; } v; v.f = f;
    const u32 u = v.u;
    return (u16)((u + 0x7fffu + ((u >> 16) & 1u)) >> 16);  // RNE, branch-free
}

// ---- Single-dispatch main (r17 base): inline W convert + gather + MFMA ----
// 512 threads / 128 rows. LDS 64KB (WsT 32K + Xs 32K) -> 2 blocks/CU.
// ONLY change vs r17: epilogue routes accumulators through LDS (reusing the
// same 64KB as float[128][128], XOR-swizzled) so Y stores become 8x
// global_store_dwordx4 per thread, 1KB contiguous per wave-instruction
// (fill-kernel pattern) instead of 32 scalar dwords over 64B segments.
__global__ __launch_bounds__(512, 4)
void gather_mfma(const float* __restrict__ X, const int* __restrict__ ind,
                 const float* __restrict__ W, float* __restrict__ Y) {
    __shared__ char lds[65536];
    u16* WsT = (u16*)lds;              // 32KB (staging phase)
    u16* Xs  = (u16*)(lds + 32768);    // 32KB (staging phase)

    const int t    = threadIdx.x;
    const int wave = t >> 6;
    const int lane = t & 63;

    // XCD b-affinity swizzle: grid=1024, 8 XCDs. XCD x gets bid 128x..128x+127
    // -> be in [16x,16x+16) -> exactly batch b=x (X[b] 4MB L2-resident).
    const int orig = blockIdx.x;
    const int bid  = (orig & 7) * 128 + (orig >> 3);
    const int kt = bid & 7;              // K_/ROWS = 8
    const int be = bid >> 3;
    const int e  = be & (E_ - 1);
    const int b  = be >> 4;
    const int k0 = kt * ROWS;

    // Issue the gather index load first (longest dependency chain).
    const int r   = t >> 2;              // row 0..127
    const int q   = t & 3;               // 32-elem quarter
    const int idx = ind[(size_t)be * K_ + k0 + r];

    // ---- Stage WsT inline: W[e] f32 [i][j] -> bf16 [j][i], swizzled ----
    {
        const float* We = W + (size_t)e * (I_ * J_);
#pragma unroll
        for (int u = 0; u < 8; ++u) {
            const int f4i = t + 512 * u;          // float4 id, 0..4095
            const int i   = f4i >> 5;
            const int j0  = (f4i & 31) * 4;
            const float4 w4 = reinterpret_cast<const float4*>(We)[f4i];
            const float ws[4] = {w4.x, w4.y, w4.z, w4.w};
#pragma unroll
            for (int qq = 0; qq < 4; ++qq) {
                const int j = j0 + qq;
                *(u16*)((char*)WsT + ((j * 256 + i * 2) ^ ((j & 7) << 4))) = f2bf(ws[qq]);
            }
        }
    }

    // ---- Stage Xs: gather 128 rows, convert f32->bf16 (r17 verbatim) ----
    {
        const float4* Xr = reinterpret_cast<const float4*>(X + ((size_t)b * T_ + idx) * I_) + q * 8;
        const int sx = (r & 7) << 4;
        char* xrow = (char*)Xs + r * 256;
#pragma unroll
        for (int u = 0; u < 4; ++u) {
            const float4 a = Xr[2 * u], c = Xr[2 * u + 1];
            s8v o;
            o[0] = (short)f2bf(a.x); o[1] = (short)f2bf(a.y);
            o[2] = (short)f2bf(a.z); o[3] = (short)f2bf(a.w);
            o[4] = (short)f2bf(c.x); o[5] = (short)f2bf(c.y);
            o[6] = (short)f2bf(c.z); o[7] = (short)f2bf(c.w);
            *reinterpret_cast<s8v*>(xrow + ((q * 64 + u * 16) ^ sx)) = o;
        }
    }
    __syncthreads();

    // ---- Compute (r12 body): wave = (rq, jh); 32 rows x 64 cols ----
    const int rq  = wave >> 1;          // 0..3
    const int jh  = wave & 1;
    const int g   = lane >> 4;
    const int l15 = lane & 15;
    const int sx  = (lane & 7) << 4;

    const char* xb = (const char*)Xs  + (size_t)(rq * 32 + l15) * 256;
    const char* wb = (const char*)WsT + (size_t)(jh * 64 + l15) * 256;

    // Hoist all A-fragments (8 x s8v = 32 VGPR)
    s8v af[2][4];
#pragma unroll
    for (int s = 0; s < 4; ++s) {
        const int off = (s * 64 + g * 16) ^ sx;
        af[0][s] = *reinterpret_cast<const s8v*>(xb + off);
        af[1][s] = *reinterpret_cast<const s8v*>(xb + 16 * 256 + off);
    }

    f4v acc[2][4];
#pragma unroll
    for (int tr = 0; tr < 2; ++tr)
#pragma unroll
        for (int n = 0; n < 4; ++n)
#pragma unroll
            for (int rr = 0; rr < 4; ++rr) acc[tr][n][rr] = 0.f;

#pragma unroll
    for (int s = 0; s < 4; ++s) {
        const int off = (s * 64 + g * 16) ^ sx;
#pragma unroll
        for (int n = 0; n < 4; ++n) {
            const s8v bf = *reinterpret_cast<const s8v*>(wb + n * 16 * 256 + off);
            acc[0][n] = __builtin_amdgcn_mfma_f32_16x16x32_bf16(af[0][s], bf, acc[0][n], 0, 0, 0);
            acc[1][n] = __builtin_amdgcn_mfma_f32_16x16x32_bf16(af[1][s], bf, acc[1][n], 0, 0, 0);
        }
    }
    __syncthreads();   // all LDS reads done -> safe to reuse as Ys

    // ---- Epilogue 1: scatter acc into LDS float[128][128], XOR-swizzled.
    // Logical (row,col) -> physical 16B chunk ((col>>2)^(row&7)), sub-offset
    // (col&3)*4. Per instruction: 8 distinct chunk%8 x 4 sub-banks = 32 banks,
    // 2 lanes/bank (free). ----
#pragma unroll
    for (int tr = 0; tr < 2; ++tr)
#pragma unroll
        for (int n = 0; n < 4; ++n) {
            const int col = jh * 64 + n * 16 + l15;
#pragma unroll
            for (int rr = 0; rr < 4; ++rr) {
                const int row = rq * 32 + tr * 16 + g * 4 + rr;
                const int ch  = (col >> 2) ^ (row & 7);
                *(float*)(lds + row * 512 + ch * 16 + (col & 3) * 4) = acc[tr][n][rr];
            }
        }
    __syncthreads();

    // ---- Epilogue 2: row-major read-back + dwordx4 stores.
    // Per instruction (fixed u): 512 threads cover 16 complete rows; each
    // wave covers 2 rows = 1KB contiguous global writes. ----
    float* Yb = Y + ((size_t)be * K_ + k0) * J_;
#pragma unroll
    for (int u = 0; u < 8; ++u) {
        const int c   = t + 512 * u;     // chunk id 0..4095
        const int row = c >> 5;
        const int c5  = c & 31;
        const float4 v = *(const float4*)(lds + row * 512 + ((c5 ^ (row & 7)) << 4));
        *reinterpret_cast<float4*>(Yb + (size_t)row * J_ + c5 * 4) = v;
    }
}

extern "C" void kernel_launch(void* const* d_in, const int* in_sizes, int n_in,
                              void* d_out, int out_size, void* d_ws, size_t ws_size,
                              hipStream_t stream) {
    (void)in_sizes; (void)n_in; (void)out_size; (void)d_ws; (void)ws_size;
    const float* X   = (const float*)d_in[0];
    const int*   ind = (const int*)d_in[1];
    const float* W   = (const float*)d_in[2];
    float*       Y   = (float*)d_out;

    const int grid = B_ * E_ * (K_ / ROWS);   // 1024
    hipLaunchKernelGGL(gather_mfma, dim3(grid), dim3(512), 0, stream,
                       X, ind, W, Y);
}

// Round 19
// 28.816 us; speedup vs baseline: 1.1537x; 1.1537x over previous
//
#include <hip/hip_runtime.h>

// Y[b,e,k,j] = sum_i X[b, ind[b,e,k], i] * W[e,i,j]
// X:[B,T,I] f32, ind:[B,E,K] int32, W:[E,I,J] f32 -> Y:[B,E,K,J] f32
#define B_ 8
#define T_ 8192
#define I_ 128
#define E_ 16
#define J_ 128
#define K_ 1024
#define ROWS 128   // k-rows per block (512 threads)

typedef unsigned short u16;
typedef unsigned int   u32;
typedef __attribute__((ext_vector_type(8))) short s8v;   // 8 bf16 = 4 VGPRs
typedef __attribute__((ext_vector_type(4))) float f4v;   // MFMA accumulator

__device__ __forceinline__ u16 f2bf(float f) {
    union { float f; u32 u; } v; v.f = f;
    const u32 u = v.u;
    return (u16)((u + 0x7fffu + ((u >> 16) & 1u)) >> 16);  // RNE, branch-free
}

// ---- Single-dispatch main (r17 verbatim): inline W convert + gather + MFMA ----
// 512 threads / 128 rows. LDS: WsT 32KB + Xs 32KB = 64KB -> 2 blocks/CU
// (16 waves/CU). Each block transposes+converts its expert's W (coalesced
// float4, L2-hot) straight into the swizzled [j][i] LDS image — no prepass
// dispatch. Scalar row-stores (all vectorized-store variants convicted:
// r7/r10 swap-scatter +3us, r18 LDS-transpose +4.5us).
__global__ __launch_bounds__(512, 4)
void gather_mfma(const float* __restrict__ X, const int* __restrict__ ind,
                 const float* __restrict__ W, float* __restrict__ Y) {
    __shared__ u16 WsT[I_ * J_];
    __shared__ u16 Xs[ROWS * I_];

    const int t    = threadIdx.x;
    const int wave = t >> 6;
    const int lane = t & 63;

    // XCD b-affinity swizzle: grid=1024, 8 XCDs. XCD x gets bid 128x..128x+127
    // -> be in [16x,16x+16) -> exactly batch b=x (X[b] 4MB L2-resident).
    const int orig = blockIdx.x;
    const int bid  = (orig & 7) * 128 + (orig >> 3);
    const int kt = bid & 7;              // K_/ROWS = 8
    const int be = bid >> 3;
    const int e  = be & (E_ - 1);
    const int b  = be >> 4;
    const int k0 = kt * ROWS;

    // Issue the gather index load first (longest dependency chain).
    const int r   = t >> 2;              // row 0..127
    const int q   = t & 3;               // 32-elem quarter
    const int idx = ind[(size_t)be * K_ + k0 + r];

    // ---- Stage WsT inline: W[e] f32 [i][j] -> bf16 [j][i], swizzled ----
    {
        const float* We = W + (size_t)e * (I_ * J_);
#pragma unroll
        for (int u = 0; u < 8; ++u) {
            const int f4i = t + 512 * u;          // float4 id, 0..4095
            const int i   = f4i >> 5;
            const int j0  = (f4i & 31) * 4;
            const float4 w4 = reinterpret_cast<const float4*>(We)[f4i];
            const float ws[4] = {w4.x, w4.y, w4.z, w4.w};
#pragma unroll
            for (int qq = 0; qq < 4; ++qq) {
                const int j = j0 + qq;
                *(u16*)((char*)WsT + ((j * 256 + i * 2) ^ ((j & 7) << 4))) = f2bf(ws[qq]);
            }
        }
    }

    // ---- Stage Xs: gather 128 rows, convert f32->bf16 ----
    {
        const float4* Xr = reinterpret_cast<const float4*>(X + ((size_t)b * T_ + idx) * I_) + q * 8;
        const int sx = (r & 7) << 4;
        char* xrow = (char*)Xs + r * 256;
#pragma unroll
        for (int u = 0; u < 4; ++u) {
            const float4 a = Xr[2 * u], c = Xr[2 * u + 1];
            s8v o;
            o[0] = (short)f2bf(a.x); o[1] = (short)f2bf(a.y);
            o[2] = (short)f2bf(a.z); o[3] = (short)f2bf(a.w);
            o[4] = (short)f2bf(c.x); o[5] = (short)f2bf(c.y);
            o[6] = (short)f2bf(c.z); o[7] = (short)f2bf(c.w);
            *reinterpret_cast<s8v*>(xrow + ((q * 64 + u * 16) ^ sx)) = o;
        }
    }
    __syncthreads();

    // ---- Compute: wave = (row-quarter rq, j-half jh); 32 rows x 64 cols ----
    const int rq  = wave >> 1;          // 0..3
    const int jh  = wave & 1;
    const int g   = lane >> 4;
    const int l15 = lane & 15;
    const int sx  = (lane & 7) << 4;

    const char* xb = (const char*)Xs  + (size_t)(rq * 32 + l15) * 256;
    const char* wb = (const char*)WsT + (size_t)(jh * 64 + l15) * 256;

    // Hoist all A-fragments (8 x s8v = 32 VGPR)
    s8v af[2][4];
#pragma unroll
    for (int s = 0; s < 4; ++s) {
        const int off = (s * 64 + g * 16) ^ sx;
        af[0][s] = *reinterpret_cast<const s8v*>(xb + off);
        af[1][s] = *reinterpret_cast<const s8v*>(xb + 16 * 256 + off);
    }

    float* Yb = Y + ((size_t)be * K_ + k0) * J_;
    // Per n-tile: 4 B-reads, 8 MFMA, 8 scalar stores — steady stream.
#pragma unroll
    for (int n = 0; n < 4; ++n) {
        f4v acc0, acc1;
#pragma unroll
        for (int rr = 0; rr < 4; ++rr) { acc0[rr] = 0.f; acc1[rr] = 0.f; }
#pragma unroll
        for (int s = 0; s < 4; ++s) {
            const int off = (s * 64 + g * 16) ^ sx;
            const s8v bf = *reinterpret_cast<const s8v*>(wb + n * 16 * 256 + off);
            acc0 = __builtin_amdgcn_mfma_f32_16x16x32_bf16(af[0][s], bf, acc0, 0, 0, 0);
            acc1 = __builtin_amdgcn_mfma_f32_16x16x32_bf16(af[1][s], bf, acc1, 0, 0, 0);
        }
        const int col = jh * 64 + n * 16 + l15;
        const int row0 = rq * 32 + g * 4;
#pragma unroll
        for (int rr = 0; rr < 4; ++rr)
            Yb[(size_t)(row0 + rr) * J_ + col] = acc0[rr];
#pragma unroll
        for (int rr = 0; rr < 4; ++rr)
            Yb[(size_t)(row0 + 16 + rr) * J_ + col] = acc1[rr];
    }
}

extern "C" void kernel_launch(void* const* d_in, const int* in_sizes, int n_in,
                              void* d_out, int out_size, void* d_ws, size_t ws_size,
                              hipStream_t stream) {
    (void)in_sizes; (void)n_in; (void)out_size; (void)d_ws; (void)ws_size;
    const float* X   = (const float*)d_in[0];
    const int*   ind = (const int*)d_in[1];
    const float* W   = (const float*)d_in[2];
    float*       Y   = (float*)d_out;

    const int grid = B_ * E_ * (K_ / ROWS);   // 1024
    hipLaunchKernelGGL(gather_mfma, dim3(grid), dim3(512), 0, stream,
                       X, ind, W, Y);
}

// Round 20
// 28.442 us; speedup vs baseline: 1.1689x; 1.0131x over previous
//
#include <hip/hip_runtime.h>

// Y[b,e,k,j] = sum_i X[b, ind[b,e,k], i] * W[e,i,j]
// X:[B,T,I] f32, ind:[B,E,K] int32, W:[E,I,J] f32 -> Y:[B,E,K,J] f32
#define B_ 8
#define T_ 8192
#define I_ 128
#define E_ 16
#define J_ 128
#define K_ 1024
#define ROWS 128   // k-rows per block (512 threads)

typedef unsigned short u16;
typedef unsigned int   u32;
typedef __attribute__((ext_vector_type(8))) short s8v;   // 8 bf16 = 4 VGPRs
typedef __attribute__((ext_vector_type(4))) float f4v;   // MFMA accumulator

__device__ __forceinline__ u16 f2bf(float f) {
    union { float f; u32 u; } v; v.f = f;
    const u32 u = v.u;
    return (u16)((u + 0x7fffu + ((u >> 16) & 1u)) >> 16);  // RNE, branch-free
}

// ---- Single-dispatch main (r19 base): inline W convert + gather + MFMA ----
// 512 threads / 128 rows. LDS: WsT 32KB + Xs 32KB = 64KB -> 2 blocks/CU.
// ONLY change vs r19: W-stage transpose re-tiled — thread owns (i-octet io,
// j0..j0+3): 8x float4 reads down 8 rows (full 64B lines, L2-hot), in-reg
// convert, 4x ds_write_b128 of complete (j,io) chunks. Replaces 32 scalar
// u16 swizzled writes (~16-way bank conflict, 8.9M cycles measured in r19).
__global__ __launch_bounds__(512, 4)
void gather_mfma(const float* __restrict__ X, const int* __restrict__ ind,
                 const float* __restrict__ W, float* __restrict__ Y) {
    __shared__ u16 WsT[I_ * J_];
    __shared__ u16 Xs[ROWS * I_];

    const int t    = threadIdx.x;
    const int wave = t >> 6;
    const int lane = t & 63;

    // XCD b-affinity swizzle: grid=1024, 8 XCDs. XCD x gets bid 128x..128x+127
    // -> be in [16x,16x+16) -> exactly batch b=x (X[b] 4MB L2-resident).
    const int orig = blockIdx.x;
    const int bid  = (orig & 7) * 128 + (orig >> 3);
    const int kt = bid & 7;              // K_/ROWS = 8
    const int be = bid >> 3;
    const int e  = be & (E_ - 1);
    const int b  = be >> 4;
    const int k0 = kt * ROWS;

    // Issue the gather index load first (longest dependency chain).
    const int r   = t >> 2;              // row 0..127
    const int q   = t & 3;               // 32-elem quarter
    const int idx = ind[(size_t)be * K_ + k0 + r];

    // ---- Stage WsT inline (conflict-free form): thread = (io, j0..j0+3) ----
    // Chunk (j, io) at byte (j*256 + io*16) ^ ((j&7)<<4) holds bf16
    // W[io*8 .. io*8+7][j] — identical layout to what the compute reads.
    {
        const float* We = W + (size_t)e * (I_ * J_);
        const int io = t & 15;           // i-octet 0..15
        const int j0 = (t >> 4) * 4;     // j group 0..124
        float4 w4[8];
#pragma unroll
        for (int u = 0; u < 8; ++u)
            w4[u] = *reinterpret_cast<const float4*>(We + (size_t)(io * 8 + u) * J_ + j0);
#pragma unroll
        for (int qq = 0; qq < 4; ++qq) {
            const int j = j0 + qq;
            s8v o;
#pragma unroll
            for (int u = 0; u < 8; ++u) {
                const float* wf = reinterpret_cast<const float*>(&w4[u]);
                o[u] = (short)f2bf(wf[qq]);
            }
            *reinterpret_cast<s8v*>((char*)WsT + ((j * 256 + io * 16) ^ ((j & 7) << 4))) = o;
        }
    }

    // ---- Stage Xs: gather 128 rows, convert f32->bf16 (r19 verbatim) ----
    {
        const float4* Xr = reinterpret_cast<const float4*>(X + ((size_t)b * T_ + idx) * I_) + q * 8;
        const int sx = (r & 7) << 4;
        char* xrow = (char*)Xs + r * 256;
#pragma unroll
        for (int u = 0; u < 4; ++u) {
            const float4 a = Xr[2 * u], c = Xr[2 * u + 1];
            s8v o;
            o[0] = (short)f2bf(a.x); o[1] = (short)f2bf(a.y);
            o[2] = (short)f2bf(a.z); o[3] = (short)f2bf(a.w);
            o[4] = (short)f2bf(c.x); o[5] = (short)f2bf(c.y);
            o[6] = (short)f2bf(c.z); o[7] = (short)f2bf(c.w);
            *reinterpret_cast<s8v*>(xrow + ((q * 64 + u * 16) ^ sx)) = o;
        }
    }
    __syncthreads();

    // ---- Compute (r19 verbatim): wave = (rq, jh); 32 rows x 64 cols ----
    const int rq  = wave >> 1;          // 0..3
    const int jh  = wave & 1;
    const int g   = lane >> 4;
    const int l15 = lane & 15;
    const int sx  = (lane & 7) << 4;

    const char* xb = (const char*)Xs  + (size_t)(rq * 32 + l15) * 256;
    const char* wb = (const char*)WsT + (size_t)(jh * 64 + l15) * 256;

    // Hoist all A-fragments (8 x s8v = 32 VGPR)
    s8v af[2][4];
#pragma unroll
    for (int s = 0; s < 4; ++s) {
        const int off = (s * 64 + g * 16) ^ sx;
        af[0][s] = *reinterpret_cast<const s8v*>(xb + off);
        af[1][s] = *reinterpret_cast<const s8v*>(xb + 16 * 256 + off);
    }

    float* Yb = Y + ((size_t)be * K_ + k0) * J_;
    // Per n-tile: 4 B-reads, 8 MFMA, 8 scalar stores — steady stream.
#pragma unroll
    for (int n = 0; n < 4; ++n) {
        f4v acc0, acc1;
#pragma unroll
        for (int rr = 0; rr < 4; ++rr) { acc0[rr] = 0.f; acc1[rr] = 0.f; }
#pragma unroll
        for (int s = 0; s < 4; ++s) {
            const int off = (s * 64 + g * 16) ^ sx;
            const s8v bf = *reinterpret_cast<const s8v*>(wb + n * 16 * 256 + off);
            acc0 = __builtin_amdgcn_mfma_f32_16x16x32_bf16(af[0][s], bf, acc0, 0, 0, 0);
            acc1 = __builtin_amdgcn_mfma_f32_16x16x32_bf16(af[1][s], bf, acc1, 0, 0, 0);
        }
        const int col = jh * 64 + n * 16 + l15;
        const int row0 = rq * 32 + g * 4;
#pragma unroll
        for (int rr = 0; rr < 4; ++rr)
            Yb[(size_t)(row0 + rr) * J_ + col] = acc0[rr];
#pragma unroll
        for (int rr = 0; rr < 4; ++rr)
            Yb[(size_t)(row0 + 16 + rr) * J_ + col] = acc1[rr];
    }
}

extern "C" void kernel_launch(void* const* d_in, const int* in_sizes, int n_in,
                              void* d_out, int out_size, void* d_ws, size_t ws_size,
                              hipStream_t stream) {
    (void)in_sizes; (void)n_in; (void)out_size; (void)d_ws; (void)ws_size;
    const float* X   = (const float*)d_in[0];
    const int*   ind = (const int*)d_in[1];
    const float* W   = (const float*)d_in[2];
    float*       Y   = (float*)d_out;

    const int grid = B_ * E_ * (K_ / ROWS);   // 1024
    hipLaunchKernelGGL(gather_mfma, dim3(grid), dim3(512), 0, stream,
                       X, ind, W, Y);
}

// Round 21
// 28.054 us; speedup vs baseline: 1.1850x; 1.0138x over previous
//
#include <hip/hip_runtime.h>

// Y[b,e,k,j] = sum_i X[b, ind[b,e,k], i] * W[e,i,j]
// X:[B,T,I] f32, ind:[B,E,K] int32, W:[E,I,J] f32 -> Y:[B,E,K,J] f32
#define B_ 8
#define T_ 8192
#define I_ 128
#define E_ 16
#define J_ 128
#define K_ 1024
#define ROWS 128   // k-rows per tile; 2 tiles per block (512 threads)

typedef unsigned short u16;
typedef unsigned int   u32;
typedef __attribute__((ext_vector_type(8))) short s8v;   // 8 bf16 = 4 VGPRs
typedef __attribute__((ext_vector_type(4))) float f4v;   // MFMA accumulator

__device__ __forceinline__ u16 f2bf(float f) {
    union { float f; u32 u; } v; v.f = f;
    const u32 u = v.u;
    return (u16)((u + 0x7fffu + ((u >> 16) & 1u)) >> 16);  // RNE, branch-free
}

// ---- Single-dispatch, all-resident main (r20 base): inline W convert +
// gather + MFMA; 2 k-tiles per block, T14 issue-early pipeline.
// grid 512 = exactly 2 blocks/CU (64KB LDS each), one round, no tail.
// W converted once per 256 rows (half of r20's redundancy). Tile-1 X loads
// issue into registers before tile-0 compute; HBM latency hides under MFMA.
__global__ __launch_bounds__(512, 4)
void gather_mfma(const float* __restrict__ X, const int* __restrict__ ind,
                 const float* __restrict__ W, float* __restrict__ Y) {
    __shared__ u16 WsT[I_ * J_];
    __shared__ u16 Xs[ROWS * I_];

    const int t    = threadIdx.x;
    const int wave = t >> 6;
    const int lane = t & 63;

    // XCD b-affinity swizzle: grid=512, 8 XCDs. XCD x gets bid 64x..64x+63
    // -> b = bid>>6 = x (X[b] 4MB L2-resident per XCD).
    const int orig = blockIdx.x;
    const int bid  = (orig & 7) * 64 + (orig >> 3);
    const int kh = bid & 3;              // K/256 = 4 double-tiles
    const int be = bid >> 2;
    const int e  = be & (E_ - 1);
    const int b  = be >> 4;
    const int k0 = kh * (2 * ROWS);

    // Gather geometry + both tiles' indices up-front (longest dep chains).
    const int r   = t >> 2;              // row 0..127
    const int q   = t & 3;               // 32-float quarter
    const int idx0 = ind[(size_t)be * K_ + k0 + r];
    const int idx1 = ind[(size_t)be * K_ + k0 + ROWS + r];

    // ---- Stage WsT inline (r20 conflict-free form): thread = (io, j0..+3),
    // 8x float4 reads down 8 rows, in-reg cvt, 4x ds_write_b128 chunks ----
    {
        const float* We = W + (size_t)e * (I_ * J_);
        const int io = t & 15;           // i-octet 0..15
        const int j0 = (t >> 4) * 4;     // j group 0..124
        float4 w4[8];
#pragma unroll
        for (int u = 0; u < 8; ++u)
            w4[u] = *reinterpret_cast<const float4*>(We + (size_t)(io * 8 + u) * J_ + j0);
#pragma unroll
        for (int qq = 0; qq < 4; ++qq) {
            const int j = j0 + qq;
            s8v o;
#pragma unroll
            for (int u = 0; u < 8; ++u) {
                const float* wf = reinterpret_cast<const float*>(&w4[u]);
                o[u] = (short)f2bf(wf[qq]);
            }
            *reinterpret_cast<s8v*>((char*)WsT + ((j * 256 + io * 16) ^ ((j & 7) << 4))) = o;
        }
    }

    // X staging helpers (r20 pattern, reg-buffered for issue-early)
    const int sxr = (r & 7) << 4;
    char* xrow = (char*)Xs + r * 256;
    float4 v[8];
    auto load_rows = [&](int idxv) {
        const float4* Xr = reinterpret_cast<const float4*>(X + ((size_t)b * T_ + idxv) * I_) + q * 8;
#pragma unroll
        for (int u = 0; u < 8; ++u) v[u] = Xr[u];
    };
    auto pack_write = [&]() {
#pragma unroll
        for (int u = 0; u < 4; ++u) {
            const float4 a = v[2 * u], c = v[2 * u + 1];
            s8v o;
            o[0] = (short)f2bf(a.x); o[1] = (short)f2bf(a.y);
            o[2] = (short)f2bf(a.z); o[3] = (short)f2bf(a.w);
            o[4] = (short)f2bf(c.x); o[5] = (short)f2bf(c.y);
            o[6] = (short)f2bf(c.z); o[7] = (short)f2bf(c.w);
            *reinterpret_cast<s8v*>(xrow + ((q * 64 + u * 16) ^ sxr)) = o;
        }
    };

    // ---- Tile 0 stage ----
    load_rows(idx0);
    pack_write();
    __syncthreads();

    // ---- Compute decomposition (r20 verbatim) ----
    const int rq  = wave >> 1;          // 0..3
    const int jh  = wave & 1;
    const int g   = lane >> 4;
    const int l15 = lane & 15;
    const int sx  = (lane & 7) << 4;
    const char* xb = (const char*)Xs  + (size_t)(rq * 32 + l15) * 256;
    const char* wb = (const char*)WsT + (size_t)(jh * 64 + l15) * 256;

    auto compute_store = [&](int kbase) {
        s8v af[2][4];
#pragma unroll
        for (int s = 0; s < 4; ++s) {
            const int off = (s * 64 + g * 16) ^ sx;
            af[0][s] = *reinterpret_cast<const s8v*>(xb + off);
            af[1][s] = *reinterpret_cast<const s8v*>(xb + 16 * 256 + off);
        }
        float* Yb = Y + ((size_t)be * K_ + kbase) * J_;
#pragma unroll
        for (int n = 0; n < 4; ++n) {
            f4v acc0, acc1;
#pragma unroll
            for (int rr = 0; rr < 4; ++rr) { acc0[rr] = 0.f; acc1[rr] = 0.f; }
#pragma unroll
            for (int s = 0; s < 4; ++s) {
                const int off = (s * 64 + g * 16) ^ sx;
                const s8v bf = *reinterpret_cast<const s8v*>(wb + n * 16 * 256 + off);
                acc0 = __builtin_amdgcn_mfma_f32_16x16x32_bf16(af[0][s], bf, acc0, 0, 0, 0);
                acc1 = __builtin_amdgcn_mfma_f32_16x16x32_bf16(af[1][s], bf, acc1, 0, 0, 0);
            }
            const int col = jh * 64 + n * 16 + l15;
            const int row0 = rq * 32 + g * 4;
#pragma unroll
            for (int rr = 0; rr < 4; ++rr)
                Yb[(size_t)(row0 + rr) * J_ + col] = acc0[rr];
#pragma unroll
            for (int rr = 0; rr < 4; ++rr)
                Yb[(size_t)(row0 + 16 + rr) * J_ + col] = acc1[rr];
        }
    };

    // ---- T14 issue-early: tile-1 loads in flight across tile-0 compute ----
    load_rows(idx1);
    compute_store(k0);
    __syncthreads();     // all Xs reads (tile 0) done
    pack_write();        // write tile 1
    __syncthreads();
    compute_store(k0 + ROWS);
}

extern "C" void kernel_launch(void* const* d_in, const int* in_sizes, int n_in,
                              void* d_out, int out_size, void* d_ws, size_t ws_size,
                              hipStream_t stream) {
    (void)in_sizes; (void)n_in; (void)out_size; (void)d_ws; (void)ws_size;
    const float* X   = (const float*)d_in[0];
    const int*   ind = (const int*)d_in[1];
    const float* W   = (const float*)d_in[2];
    float*       Y   = (float*)d_out;

    const int grid = B_ * E_ * (K_ / (2 * ROWS));   // 512, all-resident
    hipLaunchKernelGGL(gather_mfma, dim3(grid), dim3(512), 0, stream,
                       X, ind, W, Y);
}

// Round 22
// 24.955 us; speedup vs baseline: 1.3322x; 1.1242x over previous
//
#include <hip/hip_runtime.h>

// Y[b,e,k,j] = sum_i X[b, ind[b,e,k], i] * W[e,i,j]
// X:[B,T,I] f32, ind:[B,E,K] int32, W:[E,I,J] f32 -> Y:[B,E,K,J] f32
#define B_ 8
#define T_ 8192
#define I_ 128
#define E_ 16
#define J_ 128
#define K_ 1024
#define ROWS 128   // k-rows per tile; 2 tiles per block (512 threads)

typedef unsigned short u16;
typedef unsigned int   u32;
typedef __attribute__((ext_vector_type(8))) short s8v;   // 8 bf16 = 4 VGPRs
typedef __attribute__((ext_vector_type(4))) float f4v;   // MFMA accumulator

__device__ __forceinline__ u16 f2bf(float f) {
    union { float f; u32 u; } v; v.f = f;
    const u32 u = v.u;
    return (u16)((u + 0x7fffu + ((u >> 16) & 1u)) >> 16);  // RNE, branch-free
}

// ---- Single-dispatch, all-resident main (r21 base): inline W convert +
// gather + MFMA; 2 k-tiles/block, T14 issue-early.
// ONLY change vs r21: X gather re-laned for PER-INSTRUCTION coalescing —
// lane (ch=lane&31, rsub=lane>>5), row = wave*2+rsub+16u: each wave-load
// covers 2 complete rows (512B contiguous each, 16 full lines) instead of
// 64 scattered 16B chunks across 16 rows. Same bytes, 4x fewer transactions.
// LDS image byte-identical (XOR swizzle on bits 4-6 never touches bit 3).
__global__ __launch_bounds__(512, 4)
void gather_mfma(const float* __restrict__ X, const int* __restrict__ ind,
                 const float* __restrict__ W, float* __restrict__ Y) {
    __shared__ u16 WsT[I_ * J_];
    __shared__ u16 Xs[ROWS * I_];

    const int t    = threadIdx.x;
    const int wave = t >> 6;
    const int lane = t & 63;

    // XCD b-affinity swizzle: grid=512, 8 XCDs. XCD x gets bid 64x..64x+63
    // -> b = bid>>6 = x (X[b] 4MB L2-resident per XCD).
    const int orig = blockIdx.x;
    const int bid  = (orig & 7) * 64 + (orig >> 3);
    const int kh = bid & 3;              // K/256 = 4 double-tiles
    const int be = bid >> 2;
    const int e  = be & (E_ - 1);
    const int b  = be >> 4;
    const int k0 = kh * (2 * ROWS);

    // Gather lane geometry + all token indices up-front.
    const int ch   = lane & 31;          // f4 chunk within a row (0..31)
    const int rsub = lane >> 5;          // 0/1: which of the wave's 2 rows
    int idxA[8], idxB[8];
#pragma unroll
    for (int u = 0; u < 8; ++u) {
        const int rw = wave * 2 + rsub + 16 * u;   // 0..127, all distinct
        idxA[u] = ind[(size_t)be * K_ + k0 + rw];
        idxB[u] = ind[(size_t)be * K_ + k0 + ROWS + rw];
    }

    // ---- Stage WsT inline (r20/r21 conflict-free form) ----
    {
        const float* We = W + (size_t)e * (I_ * J_);
        const int io = t & 15;           // i-octet 0..15
        const int j0 = (t >> 4) * 4;     // j group 0..124
        float4 w4[8];
#pragma unroll
        for (int u = 0; u < 8; ++u)
            w4[u] = *reinterpret_cast<const float4*>(We + (size_t)(io * 8 + u) * J_ + j0);
#pragma unroll
        for (int qq = 0; qq < 4; ++qq) {
            const int j = j0 + qq;
            s8v o;
#pragma unroll
            for (int u = 0; u < 8; ++u) {
                const float* wf = reinterpret_cast<const float*>(&w4[u]);
                o[u] = (short)f2bf(wf[qq]);
            }
            *reinterpret_cast<s8v*>((char*)WsT + ((j * 256 + io * 16) ^ ((j & 7) << 4))) = o;
        }
    }

    // X staging helpers: per-instruction-coalesced loads, b64 swizzled writes.
    float4 v[8];
    auto load_rows = [&](const int* idxs) {
#pragma unroll
        for (int u = 0; u < 8; ++u)
            v[u] = reinterpret_cast<const float4*>(X + ((size_t)b * T_ + idxs[u]) * I_)[ch];
    };
    auto pack_write = [&]() {
#pragma unroll
        for (int u = 0; u < 8; ++u) {
            const int rw = wave * 2 + rsub + 16 * u;
            const float4 a = v[u];
            uint2 o;
            o.x = ((u32)f2bf(a.y) << 16) | f2bf(a.x);
            o.y = ((u32)f2bf(a.w) << 16) | f2bf(a.z);
            *reinterpret_cast<uint2*>((char*)Xs + rw * 256 + ((ch * 8) ^ ((rw & 7) << 4))) = o;
        }
    };

    // ---- Tile 0 stage ----
    load_rows(idxA);
    pack_write();
    __syncthreads();

    // ---- Compute decomposition (r21 verbatim) ----
    const int rq  = wave >> 1;          // 0..3
    const int jh  = wave & 1;
    const int g   = lane >> 4;
    const int l15 = lane & 15;
    const int sx  = (lane & 7) << 4;
    const char* xb = (const char*)Xs  + (size_t)(rq * 32 + l15) * 256;
    const char* wb = (const char*)WsT + (size_t)(jh * 64 + l15) * 256;

    auto compute_store = [&](int kbase) {
        s8v af[2][4];
#pragma unroll
        for (int s = 0; s < 4; ++s) {
            const int off = (s * 64 + g * 16) ^ sx;
            af[0][s] = *reinterpret_cast<const s8v*>(xb + off);
            af[1][s] = *reinterpret_cast<const s8v*>(xb + 16 * 256 + off);
        }
        float* Yb = Y + ((size_t)be * K_ + kbase) * J_;
#pragma unroll
        for (int n = 0; n < 4; ++n) {
            f4v acc0, acc1;
#pragma unroll
            for (int rr = 0; rr < 4; ++rr) { acc0[rr] = 0.f; acc1[rr] = 0.f; }
#pragma unroll
            for (int s = 0; s < 4; ++s) {
                const int off = (s * 64 + g * 16) ^ sx;
                const s8v bf = *reinterpret_cast<const s8v*>(wb + n * 16 * 256 + off);
                acc0 = __builtin_amdgcn_mfma_f32_16x16x32_bf16(af[0][s], bf, acc0, 0, 0, 0);
                acc1 = __builtin_amdgcn_mfma_f32_16x16x32_bf16(af[1][s], bf, acc1, 0, 0, 0);
            }
            const int col = jh * 64 + n * 16 + l15;
            const int row0 = rq * 32 + g * 4;
#pragma unroll
            for (int rr = 0; rr < 4; ++rr)
                Yb[(size_t)(row0 + rr) * J_ + col] = acc0[rr];
#pragma unroll
            for (int rr = 0; rr < 4; ++rr)
                Yb[(size_t)(row0 + 16 + rr) * J_ + col] = acc1[rr];
        }
    };

    // ---- T14 issue-early: tile-1 loads in flight across tile-0 compute ----
    load_rows(idxB);
    compute_store(k0);
    __syncthreads();     // all Xs reads (tile 0) done
    pack_write();        // write tile 1
    __syncthreads();
    compute_store(k0 + ROWS);
}

extern "C" void kernel_launch(void* const* d_in, const int* in_sizes, int n_in,
                              void* d_out, int out_size, void* d_ws, size_t ws_size,
                              hipStream_t stream) {
    (void)in_sizes; (void)n_in; (void)out_size; (void)d_ws; (void)ws_size;
    const float* X   = (const float*)d_in[0];
    const int*   ind = (const int*)d_in[1];
    const float* W   = (const float*)d_in[2];
    float*       Y   = (float*)d_out;

    const int grid = B_ * E_ * (K_ / (2 * ROWS));   // 512, all-resident
    hipLaunchKernelGGL(gather_mfma, dim3(grid), dim3(512), 0, stream,
                       X, ind, W, Y);
}

// Round 23
// 24.411 us; speedup vs baseline: 1.3619x; 1.0223x over previous
//
#include <hip/hip_runtime.h>

// Y[b,e,k,j] = sum_i X[b, ind[b,e,k], i] * W[e,i,j]
// X:[B,T,I] f32, ind:[B,E,K] int32, W:[E,I,J] f32 -> Y:[B,E,K,J] f32
#define B_ 8
#define T_ 8192
#define I_ 128
#define E_ 16
#define J_ 128
#define K_ 1024
#define TR 64      // k-rows per tile; 4 tiles per block (512 threads)

typedef unsigned short u16;
typedef unsigned int   u32;
typedef __attribute__((ext_vector_type(8))) short s8v;   // 8 bf16 = 4 VGPRs
typedef __attribute__((ext_vector_type(4))) float f4v;   // MFMA accumulator

__device__ __forceinline__ u16 f2bf(float f) {
    union { float f; u32 u; } v; v.f = f;
    const u32 u = v.u;
    return (u16)((u + 0x7fffu + ((u >> 16) & 1u)) >> 16);  // RNE, branch-free
}

// ---- Single-dispatch, all-resident main (r22 base): inline W convert +
// per-instruction-coalesced gather + MFMA.
// ONLY change vs r22: 4 tiles of 64 rows with double-buffered Xs
// (WsT 32K + XsA 16K + XsB 16K = 64KB, 2 blocks/CU). Per tile: issue next
// loads -> compute current buf -> pack_write next buf -> ONE barrier
// (vs r22's exposed bar->pack_write->bar); finer cross-wave phase mixing.
// Buffer hazard: writes at tile t+1 target the buffer last read at t-1,
// drained by t-1's barrier.
__global__ __launch_bounds__(512, 4)
void gather_mfma(const float* __restrict__ X, const int* __restrict__ ind,
                 const float* __restrict__ W, float* __restrict__ Y) {
    __shared__ u16 WsT[I_ * J_];
    __shared__ u16 XsA[TR * I_];
    __shared__ u16 XsB[TR * I_];

    const int t    = threadIdx.x;
    const int wave = t >> 6;
    const int lane = t & 63;

    // XCD b-affinity swizzle: grid=512, 8 XCDs. XCD x gets bid 64x..64x+63
    // -> b = bid>>6 = x (X[b] 4MB L2-resident per XCD).
    const int orig = blockIdx.x;
    const int bid  = (orig & 7) * 64 + (orig >> 3);
    const int kh = bid & 3;              // K/256 = 4 quad-tiles
    const int be = bid >> 2;
    const int e  = be & (E_ - 1);
    const int b  = be >> 4;
    const int k0 = kh * (4 * TR);        // 256-row range

    // Gather lane geometry + all 16 token indices up-front.
    const int ch   = lane & 31;          // f4 chunk within a row (0..31)
    const int rsub = lane >> 5;          // 0/1
    int idx[4][4];
#pragma unroll
    for (int tt = 0; tt < 4; ++tt)
#pragma unroll
        for (int u = 0; u < 4; ++u) {
            const int rw = wave * 2 + rsub + 16 * u;    // 0..63, distinct
            idx[tt][u] = ind[(size_t)be * K_ + k0 + tt * TR + rw];
        }

    // ---- Stage WsT inline (r20/r22 conflict-free form) ----
    {
        const float* We = W + (size_t)e * (I_ * J_);
        const int io = t & 15;           // i-octet 0..15
        const int j0 = (t >> 4) * 4;     // j group 0..124
        float4 w4[8];
#pragma unroll
        for (int u = 0; u < 8; ++u)
            w4[u] = *reinterpret_cast<const float4*>(We + (size_t)(io * 8 + u) * J_ + j0);
#pragma unroll
        for (int qq = 0; qq < 4; ++qq) {
            const int j = j0 + qq;
            s8v o;
#pragma unroll
            for (int u = 0; u < 8; ++u) {
                const float* wf = reinterpret_cast<const float*>(&w4[u]);
                o[u] = (short)f2bf(wf[qq]);
            }
            *reinterpret_cast<s8v*>((char*)WsT + ((j * 256 + io * 16) ^ ((j & 7) << 4))) = o;
        }
    }

    // X staging: per-instruction-coalesced loads (2 full rows / wave-instr),
    // uint2 swizzled LDS writes (r22 pattern, 4 rows/tile/thread).
    float4 v[4];
    auto load_rows = [&](const int (&ii)[4]) {
#pragma unroll
        for (int u = 0; u < 4; ++u)
            v[u] = reinterpret_cast<const float4*>(X + ((size_t)b * T_ + ii[u]) * I_)[ch];
    };
    auto pack_write = [&](u16* Xs) {
#pragma unroll
        for (int u = 0; u < 4; ++u) {
            const int rw = wave * 2 + rsub + 16 * u;
            const float4 a = v[u];
            uint2 o;
            o.x = ((u32)f2bf(a.y) << 16) | f2bf(a.x);
            o.y = ((u32)f2bf(a.w) << 16) | f2bf(a.z);
            *reinterpret_cast<uint2*>((char*)Xs + rw * 256 + ((ch * 8) ^ ((rw & 7) << 4))) = o;
        }
    };

    // ---- Compute decomposition: wave = (rq 0..3, jh); 16 rows x 64 cols ----
    const int rq  = wave >> 1;
    const int jh  = wave & 1;
    const int g   = lane >> 4;
    const int l15 = lane & 15;
    const int sx  = (lane & 7) << 4;
    const char* wb = (const char*)WsT + (size_t)(jh * 64 + l15) * 256;

    auto compute_store = [&](const u16* Xs, int kbase) {
        const char* xb = (const char*)Xs + (size_t)(rq * 16 + l15) * 256;
        s8v af[4];
#pragma unroll
        for (int s = 0; s < 4; ++s) {
            const int off = (s * 64 + g * 16) ^ sx;
            af[s] = *reinterpret_cast<const s8v*>(xb + off);
        }
        float* Yb = Y + ((size_t)be * K_ + kbase) * J_;
#pragma unroll
        for (int n = 0; n < 4; ++n) {
            f4v acc;
#pragma unroll
            for (int rr = 0; rr < 4; ++rr) acc[rr] = 0.f;
#pragma unroll
            for (int s = 0; s < 4; ++s) {
                const int off = (s * 64 + g * 16) ^ sx;
                const s8v bf = *reinterpret_cast<const s8v*>(wb + n * 16 * 256 + off);
                acc = __builtin_amdgcn_mfma_f32_16x16x32_bf16(af[s], bf, acc, 0, 0, 0);
            }
            const int col = jh * 64 + n * 16 + l15;
            const int row0 = rq * 16 + g * 4;
#pragma unroll
            for (int rr = 0; rr < 4; ++rr)
                Yb[(size_t)(row0 + rr) * J_ + col] = acc[rr];
        }
    };

    // ---- Pipeline: 1 barrier per tile transition ----
    load_rows(idx[0]); pack_write(XsA);
    __syncthreads();                          // W + tile0 visible

    load_rows(idx[1]);
    compute_store(XsA, k0);
    pack_write(XsB);
    __syncthreads();

    load_rows(idx[2]);
    compute_store(XsB, k0 + TR);
    pack_write(XsA);                          // tile0 readers drained 2 bars ago
    __syncthreads();

    load_rows(idx[3]);
    compute_store(XsA, k0 + 2 * TR);
    pack_write(XsB);
    __syncthreads();

    compute_store(XsB, k0 + 3 * TR);
}

extern "C" void kernel_launch(void* const* d_in, const int* in_sizes, int n_in,
                              void* d_out, int out_size, void* d_ws, size_t ws_size,
                              hipStream_t stream) {
    (void)in_sizes; (void)n_in; (void)out_size; (void)d_ws; (void)ws_size;
    const float* X   = (const float*)d_in[0];
    const int*   ind = (const int*)d_in[1];
    const float* W   = (const float*)d_in[2];
    float*       Y   = (float*)d_out;

    const int grid = B_ * E_ * (K_ / (4 * TR));   // 512, all-resident
    hipLaunchKernelGGL(gather_mfma, dim3(grid), dim3(512), 0, stream,
                       X, ind, W, Y);
}